// Round 18
// baseline (704.886 us; speedup 1.0000x reference)
//
#include <hip/hip_runtime.h>

typedef float f32x4 __attribute__((ext_vector_type(4)));
typedef __bf16 bf16x8 __attribute__((ext_vector_type(8)));
typedef int i32x4 __attribute__((ext_vector_type(4)));
typedef unsigned short u16;
typedef unsigned short u16x4 __attribute__((ext_vector_type(4)));
typedef unsigned short u16x8 __attribute__((ext_vector_type(8)));
typedef unsigned int u32;

#define SEQ 1024
#define NBATCH 4
#define DM 1024
#define HD 4096
#define NV 32000
#define NVP 32768  // padded vocab (Ntiles = 256, divisible by 8 XCDs)
#define NT (SEQ * NBATCH)

__device__ __forceinline__ u16 f2bf(float f) {
  u32 u = __builtin_bit_cast(u32, f);
  return (u16)((u + 0x7FFFu + ((u >> 16) & 1u)) >> 16);  // RTNE
}
__device__ __forceinline__ float bf2f(u16 h) {
  return __builtin_bit_cast(float, (u32)h << 16);
}

// ---------------- fused f32 -> bf16 weight casts (4 segments, 2048 blocks) ----
__global__ __launch_bounds__(256) void cast_all_kernel(
    const float* __restrict__ wq, const float* __restrict__ wk,
    const float* __restrict__ wv, const float* __restrict__ wo,
    u16* __restrict__ wqk, u16* __restrict__ wvh, u16* __restrict__ woh) {
  long i = (long)blockIdx.x * 256 + threadIdx.x;
  const float* src;
  u16* dst;
  long off;
  if (i < 262144) {
    if (i < 131072) { src = wq; off = i; } else { src = wk; off = i - 131072; }
    dst = wqk + i * 8;  // contiguous QK pack
  } else if (i < 393216) {
    src = wv; off = i - 262144; dst = wvh + off * 8;
  } else {
    src = wo; off = i - 393216; dst = woh + off * 8;
  }
  const f32x4* p = (const f32x4*)(src + off * 8);
  f32x4 a = p[0], b = p[1];
  u16x8 o;
  o[0] = f2bf(a[0]); o[1] = f2bf(a[1]); o[2] = f2bf(a[2]); o[3] = f2bf(a[3]);
  o[4] = f2bf(b[0]); o[5] = f2bf(b[1]); o[6] = f2bf(b[2]); o[7] = f2bf(b[3]);
  *(u16x8*)dst = o;
}

// ---------------- embedding gather: f32 + bf16 copies ----------------
__global__ __launch_bounds__(256) void embed_kernel(const int* __restrict__ ids,
                                                    const float* __restrict__ tab,
                                                    float* __restrict__ ef,
                                                    u16* __restrict__ eh) {
  int t = blockIdx.x, tid = threadIdx.x;
  long id = ids[t];
  f32x4 v = *(const f32x4*)(tab + id * DM + tid * 4);
  *(f32x4*)(ef + (long)t * DM + tid * 4) = v;
  u16x4 h;
  h[0] = f2bf(v[0]); h[1] = f2bf(v[1]); h[2] = f2bf(v[2]); h[3] = f2bf(v[3]);
  *(u16x4*)(eh + (long)t * DM + tid * 4) = h;
}

// ---------------- row softmax (1024 cols), scale 1/32, bf16 out ----------------
__global__ __launch_bounds__(256) void softmax_kernel(const float* __restrict__ s,
                                                      u16* __restrict__ p) {
  int row = blockIdx.x, tid = threadIdx.x;
  const float* rp = s + (long)row * SEQ;
  f32x4 v = *(const f32x4*)(rp + tid * 4);
  float mx = fmaxf(fmaxf(v[0], v[1]), fmaxf(v[2], v[3]));
  for (int o = 32; o; o >>= 1) mx = fmaxf(mx, __shfl_xor(mx, o));
  __shared__ float red[4];
  if ((tid & 63) == 0) red[tid >> 6] = mx;
  __syncthreads();
  mx = fmaxf(fmaxf(red[0], red[1]), fmaxf(red[2], red[3]));
  const float sc = 0.03125f;  // 1/sqrt(1024)
  f32x4 e;
  e[0] = expf((v[0] - mx) * sc); e[1] = expf((v[1] - mx) * sc);
  e[2] = expf((v[2] - mx) * sc); e[3] = expf((v[3] - mx) * sc);
  float sm = e[0] + e[1] + e[2] + e[3];
  for (int o = 32; o; o >>= 1) sm += __shfl_xor(sm, o);
  __syncthreads();
  if ((tid & 63) == 0) red[tid >> 6] = sm;
  __syncthreads();
  sm = red[0] + red[1] + red[2] + red[3];
  float inv = 1.0f / sm;
  u16x4 o4;
  o4[0] = f2bf(e[0] * inv); o4[1] = f2bf(e[1] * inv);
  o4[2] = f2bf(e[2] * inv); o4[3] = f2bf(e[3] * inv);
  *(u16x4*)(p + (long)row * SEQ + tid * 4) = o4;
}

// ---------------- LayerNorm over D=1024; optional f32 and bf16 outputs ----------------
__global__ __launch_bounds__(256) void ln_kernel(const float* __restrict__ in,
                                                 const float* __restrict__ g,
                                                 const float* __restrict__ be,
                                                 float* __restrict__ outf,
                                                 u16* __restrict__ outh) {
  int row = blockIdx.x, tid = threadIdx.x;
  f32x4 v = *(const f32x4*)(in + (long)row * DM + tid * 4);
  float s = v[0] + v[1] + v[2] + v[3];
  float q = v[0] * v[0] + v[1] * v[1] + v[2] * v[2] + v[3] * v[3];
  for (int o = 32; o; o >>= 1) { s += __shfl_xor(s, o); q += __shfl_xor(q, o); }
  __shared__ float rs_[4], rq_[4];
  if ((tid & 63) == 0) { rs_[tid >> 6] = s; rq_[tid >> 6] = q; }
  __syncthreads();
  s = rs_[0] + rs_[1] + rs_[2] + rs_[3];
  q = rq_[0] + rq_[1] + rq_[2] + rq_[3];
  float mean = s * (1.0f / DM);
  float var = q * (1.0f / DM) - mean * mean;
  float rstd = rsqrtf(var + 1e-5f);
  f32x4 gg = *(const f32x4*)(g + tid * 4);
  f32x4 bb = *(const f32x4*)(be + tid * 4);
  f32x4 y;
  y[0] = (v[0] - mean) * rstd * gg[0] + bb[0];
  y[1] = (v[1] - mean) * rstd * gg[1] + bb[1];
  y[2] = (v[2] - mean) * rstd * gg[2] + bb[2];
  y[3] = (v[3] - mean) * rstd * gg[3] + bb[3];
  if (outf) *(f32x4*)(outf + (long)row * DM + tid * 4) = y;
  if (outh) {
    u16x4 h;
    h[0] = f2bf(y[0]); h[1] = f2bf(y[1]); h[2] = f2bf(y[2]); h[3] = f2bf(y[3]);
    *(u16x4*)(outh + (long)row * DM + tid * 4) = h;
  }
}

// ---------------- LayerNorm -> int8 per-row quant (+ optional f32 out) --------------
__global__ __launch_bounds__(256) void ln_i8_kernel(const float* __restrict__ in,
                                                    const float* __restrict__ g,
                                                    const float* __restrict__ be,
                                                    char* __restrict__ q8,
                                                    float* __restrict__ scale,
                                                    float* __restrict__ outf) {
  int row = blockIdx.x, tid = threadIdx.x;
  f32x4 v = *(const f32x4*)(in + (long)row * DM + tid * 4);
  float s = v[0] + v[1] + v[2] + v[3];
  float q = v[0] * v[0] + v[1] * v[1] + v[2] * v[2] + v[3] * v[3];
  for (int o = 32; o; o >>= 1) { s += __shfl_xor(s, o); q += __shfl_xor(q, o); }
  __shared__ float rs_[4], rq_[4], rm_[4];
  if ((tid & 63) == 0) { rs_[tid >> 6] = s; rq_[tid >> 6] = q; }
  __syncthreads();
  s = rs_[0] + rs_[1] + rs_[2] + rs_[3];
  q = rq_[0] + rq_[1] + rq_[2] + rq_[3];
  float mean = s * (1.0f / DM);
  float var = q * (1.0f / DM) - mean * mean;
  float rstd = rsqrtf(var + 1e-5f);
  f32x4 gg = *(const f32x4*)(g + tid * 4);
  f32x4 bb = *(const f32x4*)(be + tid * 4);
  f32x4 y;
  y[0] = (v[0] - mean) * rstd * gg[0] + bb[0];
  y[1] = (v[1] - mean) * rstd * gg[1] + bb[1];
  y[2] = (v[2] - mean) * rstd * gg[2] + bb[2];
  y[3] = (v[3] - mean) * rstd * gg[3] + bb[3];
  if (outf) *(f32x4*)(outf + (long)row * DM + tid * 4) = y;
  float am = fmaxf(fmaxf(fabsf(y[0]), fabsf(y[1])), fmaxf(fabsf(y[2]), fabsf(y[3])));
  for (int o = 32; o; o >>= 1) am = fmaxf(am, __shfl_xor(am, o));
  __syncthreads();
  if ((tid & 63) == 0) rm_[tid >> 6] = am;
  __syncthreads();
  am = fmaxf(fmaxf(rm_[0], rm_[1]), fmaxf(rm_[2], rm_[3]));
  float inv = (am > 0.f) ? 127.f / am : 0.f;
  int q0 = (int)rintf(y[0] * inv), q1 = (int)rintf(y[1] * inv);
  int q2 = (int)rintf(y[2] * inv), q3 = (int)rintf(y[3] * inv);
  u32 pk = (q0 & 255) | ((q1 & 255) << 8) | ((q2 & 255) << 16) | ((u32)(q3 & 255) << 24);
  *(u32*)(q8 + (size_t)row * DM + tid * 4) = pk;
  if (tid == 0) scale[row] = am * (1.0f / 127.f);
}

// ---------------- generic per-row f32 -> int8 quant (rowlen 1024/2048/3072/4096) ------
__global__ __launch_bounds__(256) void rowq_f32(const float* __restrict__ in,
                                                char* __restrict__ q8,
                                                float* __restrict__ scale, int rowlen) {
  const int row = blockIdx.x, tid = threadIdx.x;
  const float* rp = in + (size_t)row * rowlen;
  const int nch = rowlen >> 10;
  f32x4 v0 = {}, v1 = {}, v2 = {}, v3 = {};
  v0 = *(const f32x4*)(rp + tid * 4);
  if (nch > 1) v1 = *(const f32x4*)(rp + 1024 + tid * 4);
  if (nch > 2) v2 = *(const f32x4*)(rp + 2048 + tid * 4);
  if (nch > 3) v3 = *(const f32x4*)(rp + 3072 + tid * 4);
  auto am4 = [](f32x4 v) {
    return fmaxf(fmaxf(fabsf(v[0]), fabsf(v[1])), fmaxf(fabsf(v[2]), fabsf(v[3])));
  };
  float am = fmaxf(fmaxf(am4(v0), am4(v1)), fmaxf(am4(v2), am4(v3)));
  for (int o = 32; o; o >>= 1) am = fmaxf(am, __shfl_xor(am, o));
  __shared__ float rm_[4];
  if ((tid & 63) == 0) rm_[tid >> 6] = am;
  __syncthreads();
  am = fmaxf(fmaxf(rm_[0], rm_[1]), fmaxf(rm_[2], rm_[3]));
  const float inv = (am > 0.f) ? 127.f / am : 0.f;
  auto pack = [&](f32x4 v) {
    int q0 = (int)rintf(v[0] * inv), q1 = (int)rintf(v[1] * inv);
    int q2 = (int)rintf(v[2] * inv), q3 = (int)rintf(v[3] * inv);
    return (u32)((q0 & 255) | ((q1 & 255) << 8) | ((q2 & 255) << 16) | ((u32)(q3 & 255) << 24));
  };
  char* qp = q8 + (size_t)row * rowlen;
  *(u32*)(qp + tid * 4) = pack(v0);
  if (nch > 1) *(u32*)(qp + 1024 + tid * 4) = pack(v1);
  if (nch > 2) *(u32*)(qp + 2048 + tid * 4) = pack(v2);
  if (nch > 3) *(u32*)(qp + 3072 + tid * 4) = pack(v3);
  if (tid == 0) scale[row] = am * (1.0f / 127.f);
}

// ---------------- per-row bf16 -> int8 quant, rowlen = HD (h matrix) ----------------
__global__ __launch_bounds__(256) void rowq_bf16_hd(const u16* __restrict__ in,
                                                    char* __restrict__ q8,
                                                    float* __restrict__ scale) {
  const int row = blockIdx.x, tid = threadIdx.x;
  const u16* rp = in + (size_t)row * HD;
  f32x4 v0, v1, v2, v3;
  auto ld4 = [&](int off) {
    u16x4 h = *(const u16x4*)(rp + off + tid * 4);
    f32x4 v;
    v[0] = bf2f(h[0]); v[1] = bf2f(h[1]); v[2] = bf2f(h[2]); v[3] = bf2f(h[3]);
    return v;
  };
  v0 = ld4(0); v1 = ld4(1024); v2 = ld4(2048); v3 = ld4(3072);
  auto am4 = [](f32x4 v) {
    return fmaxf(fmaxf(fabsf(v[0]), fabsf(v[1])), fmaxf(fabsf(v[2]), fabsf(v[3])));
  };
  float am = fmaxf(fmaxf(am4(v0), am4(v1)), fmaxf(am4(v2), am4(v3)));
  for (int o = 32; o; o >>= 1) am = fmaxf(am, __shfl_xor(am, o));
  __shared__ float rm_[4];
  if ((tid & 63) == 0) rm_[tid >> 6] = am;
  __syncthreads();
  am = fmaxf(fmaxf(rm_[0], rm_[1]), fmaxf(rm_[2], rm_[3]));
  const float inv = (am > 0.f) ? 127.f / am : 0.f;
  auto pack = [&](f32x4 v) {
    int q0 = (int)rintf(v[0] * inv), q1 = (int)rintf(v[1] * inv);
    int q2 = (int)rintf(v[2] * inv), q3 = (int)rintf(v[3] * inv);
    return (u32)((q0 & 255) | ((q1 & 255) << 8) | ((q2 & 255) << 16) | ((u32)(q3 & 255) << 24));
  };
  char* qp = q8 + (size_t)row * HD;
  *(u32*)(qp + tid * 4) = pack(v0);
  *(u32*)(qp + 1024 + tid * 4) = pack(v1);
  *(u32*)(qp + 2048 + tid * 4) = pack(v2);
  *(u32*)(qp + 3072 + tid * 4) = pack(v3);
  if (tid == 0) scale[row] = am * (1.0f / 127.f);
}

#define GLD(gp, lp)                                              \
  __builtin_amdgcn_global_load_lds(                              \
      (__attribute__((address_space(1))) void*)(gp),             \
      (__attribute__((address_space(3))) void*)(lp), 16, 0, 0)

// ---------------- generic bf16 GEMM (m97 structure): C = A (MxK) * B^T ----------------
#define BM 128
#define BN 128
#define BK 32

__global__ __launch_bounds__(256) void gemm_bt(
    const u16* __restrict__ A, const u16* __restrict__ B,
    float* __restrict__ Cf, u16* __restrict__ Ch,
    const float* __restrict__ bias, const float* __restrict__ resid,
    int K, int lda, int ldb, int ldc,
    long batA, long batB, long batC, int relu) {
  __shared__ u16 As[BM * BK];
  __shared__ u16 Bs[BN * BK];
  const int tid = threadIdx.x;
  const int bz = blockIdx.z;
  A += (long)bz * batA;
  B += (long)bz * batB;
  const long cbase = (long)bz * batC;
  const int row0 = blockIdx.y * BM;
  const int col0 = blockIdx.x * BN;
  const int l = tid & 63;
  const int w = tid >> 6;
  const int wr = (w >> 1) * 64, wc = (w & 1) * 64;

  f32x4 acc[4][4] = {};

  const u16* gA = A + (long)(row0 + (tid >> 2)) * lda + (tid & 3) * 8;
  const u16* gB = B + (long)(col0 + (tid >> 2)) * ldb + (tid & 3) * 8;
  const long a64 = (long)64 * lda, b64 = (long)64 * ldb;
  u16* lA = As + tid * 8;
  u16* lB = Bs + tid * 8;

  const int fr = l & 15;
  const int fk = (l >> 4) * 8;
  const u16* rA = As + (wr + fr) * BK + fk;
  const u16* rB = Bs + (wc + fr) * BK + fk;

  for (int k0 = 0; k0 < K; k0 += BK) {
    GLD(gA + k0, lA);
    GLD(gA + a64 + k0, lA + 2048);
    GLD(gB + k0, lB);
    GLD(gB + b64 + k0, lB + 2048);
    __syncthreads();
    bf16x8 af[4], bf[4];
#pragma unroll
    for (int m = 0; m < 4; ++m) af[m] = *(const bf16x8*)(rA + m * 16 * BK);
#pragma unroll
    for (int n = 0; n < 4; ++n) bf[n] = *(const bf16x8*)(rB + n * 16 * BK);
#pragma unroll
    for (int m = 0; m < 4; ++m)
#pragma unroll
      for (int n = 0; n < 4; ++n)
        acc[m][n] = __builtin_amdgcn_mfma_f32_16x16x32_bf16(af[m], bf[n], acc[m][n], 0, 0, 0);
    __syncthreads();
  }

  const int er = row0 + wr + ((l >> 4) << 2);
  const int ec = col0 + wc + (l & 15);
#pragma unroll
  for (int m = 0; m < 4; ++m) {
#pragma unroll
    for (int n = 0; n < 4; ++n) {
      f32x4 v = acc[m][n];
      const int c = ec + n * 16;
      float bv = bias ? bias[c] : 0.0f;
#pragma unroll
      for (int i = 0; i < 4; ++i) {
        const int r = er + m * 16 + i;
        float x = v[i] + bv;
        if (resid) x += resid[(long)r * ldc + c];
        if (relu) x = fmaxf(x, 0.0f);
        if (Cf) Cf[cbase + (long)r * ldc + c] = x;
        if (Ch) Ch[cbase + (long)r * ldc + c] = f2bf(x);
      }
    }
  }
}

#define DSB() __builtin_amdgcn_sched_barrier(0)
#define SBAR() __builtin_amdgcn_s_barrier()

// ---------------- int8 GEMM, depth-2 prefetch, STATIC 3-buffer (round-13 proven) -------
// 128x128 tile, BK=64, mfma_i32_16x16x64_i8. nkt % 3 == 1. XCD chunk + N-fast order.
// Optional: f32 out (Cf), bf16 out (Ch), f32 resid, relu.
__global__ __launch_bounds__(256) void gemm_i8(
    const char* __restrict__ A, const char* __restrict__ B,
    float* __restrict__ Cf, u16* __restrict__ Ch,
    const float* __restrict__ sA, const float* __restrict__ sB,
    const float* __restrict__ bias, const float* __restrict__ resid,
    int K, int lda, int ldb, int ldc, int Mtiles, int Ntiles, int relu) {
  __shared__ __align__(16) char As[3][128 * 64];
  __shared__ __align__(16) char Bs[3][128 * 64];
  const int tid = threadIdx.x;

  const int nwg = gridDim.x;
  const int blk = blockIdx.x;
  const int cpx = nwg >> 3;
  const int wg = (blk & 7) * cpx + (blk >> 3);
  const int row0 = (wg / Ntiles) * 128;
  const int col0 = (wg % Ntiles) * 128;

  const int l = tid & 63;
  const int w = tid >> 6;
  const int wr = (w >> 1) * 64, wc = (w & 1) * 64;

  const int srow = tid >> 2;
  const int sslot = (tid & 3) ^ ((srow >> 1) & 3);
  const char* gA = A + (size_t)(row0 + srow) * lda + sslot * 16;
  const char* gB = B + (size_t)(col0 + srow) * ldb + sslot * 16;
  const size_t a64 = (size_t)64 * lda, b64 = (size_t)64 * ldb;

#define STAGE_I8(buf, kt)                                            \
  do {                                                               \
    const char* _ga = gA + (size_t)(kt) * 64;                        \
    const char* _gb = gB + (size_t)(kt) * 64;                        \
    GLD(_ga, &As[buf][0] + tid * 16);                                \
    GLD(_ga + a64, &As[buf][4096] + tid * 16);                       \
    GLD(_gb, &Bs[buf][0] + tid * 16);                                \
    GLD(_gb + b64, &Bs[buf][4096] + tid * 16);                       \
  } while (0)

  const int fr = l & 15;
  const int fsw = 16 * ((l >> 4) ^ ((fr >> 1) & 3));
  const int raoff = (wr + fr) * 64 + fsw;
  const int rboff = (wc + fr) * 64 + fsw;

  i32x4 acc[4][4] = {};

#define COMPUTE_I8(buf)                                                         \
  do {                                                                          \
    i32x4 af[4], bf[4];                                                         \
    _Pragma("unroll")                                                           \
    for (int m = 0; m < 4; ++m) af[m] = *(const i32x4*)(&As[buf][raoff + m * 1024]); \
    _Pragma("unroll")                                                           \
    for (int n = 0; n < 4; ++n) bf[n] = *(const i32x4*)(&Bs[buf][rboff + n * 1024]); \
    _Pragma("unroll")                                                           \
    for (int m = 0; m < 4; ++m)                                                 \
      _Pragma("unroll")                                                         \
      for (int n = 0; n < 4; ++n)                                               \
        acc[m][n] = __builtin_amdgcn_mfma_i32_16x16x64_i8(af[m], bf[n], acc[m][n], 0, 0, 0); \
  } while (0)

#define PIPE_STEP(bufS, kt, bufC)                    \
  do {                                               \
    STAGE_I8(bufS, kt);                              \
    COMPUTE_I8(bufC);                                \
    asm volatile("s_waitcnt vmcnt(4)"); DSB();       \
    SBAR();                                          \
  } while (0)

  const int nkt = K >> 6;  // nkt % 3 == 1 (16 for K=1024, 64 for K=4096)

  STAGE_I8(0, 0);
  STAGE_I8(1, 1);
  asm volatile("s_waitcnt vmcnt(4)"); DSB();
  SBAR();

  for (int t = 0; t + 7 <= nkt; t += 3) {
    PIPE_STEP(2, t + 2, 0);
    PIPE_STEP(0, t + 3, 1);
    PIPE_STEP(1, t + 4, 2);
  }
  PIPE_STEP(2, nkt - 2, 0);
  PIPE_STEP(0, nkt - 1, 1);
  COMPUTE_I8(2);
  asm volatile("s_waitcnt vmcnt(0)"); DSB();
  SBAR();
  COMPUTE_I8(0);

  const int er = row0 + wr + ((l >> 4) << 2);
  const int ec = col0 + wc + (l & 15);
#pragma unroll
  for (int m = 0; m < 4; ++m) {
#pragma unroll
    for (int n = 0; n < 4; ++n) {
      i32x4 v = acc[m][n];
      const int c = ec + n * 16;
      const float sb = sB[c];
      const float bv = bias ? bias[c] : 0.0f;
#pragma unroll
      for (int i = 0; i < 4; ++i) {
        const int r = er + m * 16 + i;
        float x = (float)v[i] * (sA[r] * sb) + bv;
        if (resid) x += resid[(size_t)r * ldc + c];
        if (relu) x = fmaxf(x, 0.0f);
        if (Cf) Cf[(size_t)r * ldc + c] = x;
        if (Ch) Ch[(size_t)r * ldc + c] = f2bf(x);
      }
    }
  }
#undef STAGE_I8
#undef COMPUTE_I8
#undef PIPE_STEP
}

// ---------------- int8 GEMM, N-SLICED XCD ownership + LDS-bounce f32x4 epilogue -------
// Pipeline identical to round 16. Epilogue: dequant into a 16 KB LDS quarter (reusing
// As), then cooperative float4 stores (512 B contiguous per 32 lanes) in 4 quarters.
__global__ __launch_bounds__(256) void gemm_i8_ns(
    const char* __restrict__ A, const char* __restrict__ B,
    float* __restrict__ C, const float* __restrict__ sA, const float* __restrict__ sB,
    const float* __restrict__ bias, int K, int lda, int ldb, int ldc,
    int Mtiles, int Ntiles, int validN) {
  __shared__ __align__(16) char As[3][128 * 64];
  __shared__ __align__(16) char Bs[3][128 * 64];
  const int tid = threadIdx.x;

  const int blk = blockIdx.x;
  const int xcd = blk & 7;
  const int local = blk >> 3;
  const int nsl = Ntiles >> 3;
  const int m = local / nsl;
  const int nl = local - m * nsl;
  const int row0 = m * 128;
  const int col0 = (xcd * nsl + nl) * 128;

  const int l = tid & 63;
  const int w = tid >> 6;
  const int wr = (w >> 1) * 64, wc = (w & 1) * 64;

  const int srow = tid >> 2;
  const int sslot = (tid & 3) ^ ((srow >> 1) & 3);
  const char* gA = A + (size_t)(row0 + srow) * lda + sslot * 16;
  const char* gB = B + (size_t)(col0 + srow) * ldb + sslot * 16;
  const size_t a64 = (size_t)64 * lda, b64 = (size_t)64 * ldb;

#define STAGE_NS(buf, kt)                                            \
  do {                                                               \
    const char* _ga = gA + (size_t)(kt) * 64;                        \
    const char* _gb = gB + (size_t)(kt) * 64;                        \
    GLD(_ga, &As[buf][0] + tid * 16);                                \
    GLD(_ga + a64, &As[buf][4096] + tid * 16);                       \
    GLD(_gb, &Bs[buf][0] + tid * 16);                                \
    GLD(_gb + b64, &Bs[buf][4096] + tid * 16);                       \
  } while (0)

  const int fr = l & 15;
  const int fsw = 16 * ((l >> 4) ^ ((fr >> 1) & 3));
  const int raoff = (wr + fr) * 64 + fsw;
  const int rboff = (wc + fr) * 64 + fsw;

  i32x4 acc[4][4] = {};

#define COMPUTE_NS(buf)                                                         \
  do {                                                                          \
    i32x4 af[4], bf[4];                                                         \
    _Pragma("unroll")                                                           \
    for (int m_ = 0; m_ < 4; ++m_) af[m_] = *(const i32x4*)(&As[buf][raoff + m_ * 1024]); \
    _Pragma("unroll")                                                           \
    for (int n_ = 0; n_ < 4; ++n_) bf[n_] = *(const i32x4*)(&Bs[buf][rboff + n_ * 1024]); \
    _Pragma("unroll")                                                           \
    for (int m_ = 0; m_ < 4; ++m_)                                              \
      _Pragma("unroll")                                                         \
      for (int n_ = 0; n_ < 4; ++n_)                                            \
        acc[m_][n_] = __builtin_amdgcn_mfma_i32_16x16x64_i8(af[m_], bf[n_], acc[m_][n_], 0, 0, 0); \
  } while (0)

#define PIPE_NS(bufS, kt, bufC)                      \
  do {                                               \
    STAGE_NS(bufS, kt);                              \
    COMPUTE_NS(bufC);                                \
    asm volatile("s_waitcnt vmcnt(4)"); DSB();       \
    SBAR();                                          \
  } while (0)

  const int nkt = K >> 6;

  STAGE_NS(0, 0);
  STAGE_NS(1, 1);
  asm volatile("s_waitcnt vmcnt(4)"); DSB();
  SBAR();

  for (int t = 0; t + 7 <= nkt; t += 3) {
    PIPE_NS(2, t + 2, 0);
    PIPE_NS(0, t + 3, 1);
    PIPE_NS(1, t + 4, 2);
  }
  PIPE_NS(2, nkt - 2, 0);
  PIPE_NS(0, nkt - 1, 1);
  COMPUTE_NS(2);
  asm volatile("s_waitcnt vmcnt(0)"); DSB();
  SBAR();
  COMPUTE_NS(0);

  // ---- epilogue: LDS-bounce, 4 quarters of 32 rows, fully-coalesced f32x4 stores ----
  float* fl = (float*)&As[0][0];  // 16 KB quarter buffer (pipeline finished)
  const int c_l = wc + (l & 15);
  const int rsub = (l >> 4) << 2;
#pragma unroll
  for (int qq = 0; qq < 4; ++qq) {
    __syncthreads();  // prev quarter reads done / pipeline LDS free
    if (wr == (qq >> 1) * 64) {
      const int mq0 = (qq & 1) * 2;
#pragma unroll
      for (int mm = 0; mm < 2; ++mm) {
        const int m_ = mq0 + mm;
#pragma unroll
        for (int n_ = 0; n_ < 4; ++n_) {
          i32x4 v = acc[m_][n_];
          const int cc = c_l + n_ * 16;
          const int cg = col0 + cc;
          const float sb = sB[cg];
          const float bv = (bias && cg < validN) ? bias[cg] : 0.0f;
#pragma unroll
          for (int i = 0; i < 4; ++i) {
            const int rr = mm * 16 + rsub + i;  // 0..31
            const float sa = sA[row0 + wr + m_ * 16 + rsub + i];
            fl[rr * 128 + cc] = (float)v[i] * (sa * sb) + bv;
          }
        }
      }
    }
    __syncthreads();
    const int qb = qq * 32;
#pragma unroll
    for (int j = 0; j < 4; ++j) {
      const int e = j * 256 + tid;     // 0..1023
      const int rr = e >> 5;           // 0..31
      const int c4 = (e & 31) * 4;     // 0..124
      const int cg = col0 + c4;
      if (cg < validN) {               // validN % 4 == 0 -> float4 all-or-nothing
        f32x4 vv = *(const f32x4*)&fl[rr * 128 + c4];
        *(f32x4*)&C[(size_t)(row0 + qb + rr) * ldc + cg] = vv;
      }
    }
  }
#undef STAGE_NS
#undef COMPUTE_NS
#undef PIPE_NS
}

extern "C" void kernel_launch(void* const* d_in, const int* in_sizes, int n_in,
                              void* d_out, int out_size, void* d_ws, size_t ws_size,
                              hipStream_t stream) {
  const int* ids = (const int*)d_in[0];
  const float* tab = (const float*)d_in[1];
  const float* WQ = (const float*)d_in[2];
  const float* WK = (const float*)d_in[3];
  const float* WV = (const float*)d_in[4];
  const float* Wo = (const float*)d_in[5];
  const float* bo = (const float*)d_in[6];
  const float* W1 = (const float*)d_in[7];
  const float* b1 = (const float*)d_in[8];
  const float* W2 = (const float*)d_in[9];
  const float* b2 = (const float*)d_in[10];
  const float* g1 = (const float*)d_in[11];
  const float* be1 = (const float*)d_in[12];
  const float* g2 = (const float*)d_in[13];
  const float* be2 = (const float*)d_in[14];
  const float* Wd = (const float*)d_in[15];
  const float* bd = (const float*)d_in[16];
  float* logits = (float*)d_out;

  if (ws_size < 280000000ull) return;

  char* p = (char*)d_ws;
  auto alloc = [&](size_t bytes) {
    char* r = p;
    p += (bytes + 255) & ~(size_t)255;
    return r;
  };
  float* embf = (float*)alloc((size_t)NT * DM * 4);
  u16* embh = (u16*)alloc((size_t)NT * DM * 2);
  u16* WQKh = (u16*)alloc((size_t)2 * DM * DM * 2);  // [2048][1024] packed WQ;WK
  u16* WVh = (u16*)alloc((size_t)DM * DM * 2);
  u16* Woh = (u16*)alloc((size_t)DM * DM * 2);
  char* W1q = (char*)alloc((size_t)HD * DM);         // int8 W1
  float* sW1 = (float*)alloc((size_t)HD * 4);
  char* W2q = (char*)alloc((size_t)DM * HD);         // int8 W2
  float* sW2 = (float*)alloc((size_t)DM * 4);
  char* Wdq = (char*)alloc((size_t)NVP * DM);        // int8 Wd, padded to 32768 rows
  float* sWd = (float*)alloc((size_t)NVP * 4);
  u16* QKh = (u16*)alloc((size_t)NT * 2 * DM * 2);   // [NT][2048]: Q | K
  u16* VTh = (u16*)alloc((size_t)NBATCH * DM * SEQ * 2);
  float* scoresf = (float*)alloc((size_t)NBATCH * SEQ * SEQ * 4);
  u16* Ph = (u16*)alloc((size_t)NBATCH * SEQ * SEQ * 2);
  u16* zh = (u16*)alloc((size_t)NT * DM * 2);
  float* r1f = (float*)alloc((size_t)NT * DM * 4);
  float* xf = (float*)alloc((size_t)NT * DM * 4);
  char* xq = (char*)alloc((size_t)NT * DM);          // int8 LN1 output
  float* sX = (float*)alloc((size_t)NT * 4);
  u16* hh = (u16*)alloc((size_t)NT * HD * 2);
  char* hq = (char*)alloc((size_t)NT * HD);          // int8 h
  float* sH = (float*)alloc((size_t)NT * 4);
  float* r2f = (float*)alloc((size_t)NT * DM * 4);
  char* outq = (char*)alloc((size_t)NT * DM);
  float* sOut = (float*)alloc((size_t)NT * 4);

  // --- weight casts (4 segments, 2048 blocks) + int8 weight quants ---
  cast_all_kernel<<<dim3(2048), 256, 0, stream>>>(WQ, WK, WV, Wo, WQKh, WVh, Woh);
  rowq_f32<<<dim3(NV), 256, 0, stream>>>(Wd, Wdq, sWd, DM);
  rowq_f32<<<dim3(HD), 256, 0, stream>>>(W1, W1q, sW1, DM);
  rowq_f32<<<dim3(DM), 256, 0, stream>>>(W2, W2q, sW2, HD);

  // --- embedding ---
  embed_kernel<<<NT, 256, 0, stream>>>(ids, tab, embf, embh);

  // --- fused Q,K projection: QK[t][0..1023]=Q, [1024..2047]=K ---
  gemm_bt<<<dim3(2 * DM / BN, NT / BM, 1), 256, 0, stream>>>(
      embh, WQKh, nullptr, QKh, nullptr, nullptr, DM, DM, DM, 2 * DM, 0, 0, 0, 0);

  // --- V^T per batch ---
  gemm_bt<<<dim3(SEQ / BN, DM / BM, NBATCH), 256, 0, stream>>>(
      WVh, embh, nullptr, VTh, nullptr, nullptr, DM, DM, NBATCH * DM, SEQ,
      0, DM, (long)DM * SEQ, 0);

  // --- scores ---
  gemm_bt<<<dim3(SEQ / BN, SEQ / BM, NBATCH), 256, 0, stream>>>(
      QKh, QKh + DM, scoresf, nullptr, nullptr, nullptr, DM,
      NBATCH * 2 * DM, NBATCH * 2 * DM, SEQ,
      2 * DM, 2 * DM, (long)SEQ * SEQ, 0);

  softmax_kernel<<<NBATCH * SEQ, 256, 0, stream>>>(scoresf, Ph);

  // --- Z = P @ V^T ---
  gemm_bt<<<dim3(DM / BN, SEQ / BM, NBATCH), 256, 0, stream>>>(
      Ph, VTh, nullptr, zh, nullptr, nullptr, SEQ, SEQ, SEQ, NBATCH * DM,
      (long)SEQ * SEQ, (long)DM * SEQ, DM, 0);

  // --- r1 = z @ Wo^T + bo + emb ---
  gemm_bt<<<dim3(DM / BN, NT / BM, 1), 256, 0, stream>>>(
      zh, Woh, r1f, nullptr, bo, embf, DM, DM, DM, DM, 0, 0, 0, 0);

  // --- LN1 -> int8 (+ f32 for FFN2 resid) ---
  ln_i8_kernel<<<NT, 256, 0, stream>>>(r1f, g1, be1, xq, sX, xf);

  // --- FFN1: int8 GEMM (K=1024, nkt=16), relu, bf16 out ---
  gemm_i8<<<dim3((NT / 128) * (HD / 128)), 256, 0, stream>>>(
      xq, W1q, nullptr, hh, sX, sW1, b1, nullptr, DM, DM, DM, HD,
      NT / 128, HD / 128, 1);

  // --- h -> int8 per-row ---
  rowq_bf16_hd<<<dim3(NT), 256, 0, stream>>>(hh, hq, sH);

  // --- FFN2: int8 GEMM depth-2 (K=4096, nkt=64), resid = xf, bias = b2 ---
  gemm_i8<<<dim3((NT / 128) * (DM / 128)), 256, 0, stream>>>(
      hq, W2q, r2f, nullptr, sH, sW2, b2, xf, HD, HD, HD, DM,
      NT / 128, DM / 128, 0);

  // --- LN2 -> int8 + per-row scale ---
  ln_i8_kernel<<<NT, 256, 0, stream>>>(r2f, g2, be2, outq, sOut, nullptr);

  // --- logits: int8 GEMM, N-sliced XCD ownership + vectorized epilogue ---
  gemm_i8_ns<<<dim3((NT / 128) * (NVP / 128)), 256, 0, stream>>>(
      outq, Wdq, logits, sOut, sWd, bd, DM, DM, DM, NV,
      NT / 128, NVP / 128, NV);
}

// Round 19
// 648.914 us; speedup vs baseline: 1.0863x; 1.0863x over previous
//
#include <hip/hip_runtime.h>

typedef float f32x4 __attribute__((ext_vector_type(4)));
typedef __bf16 bf16x8 __attribute__((ext_vector_type(8)));
typedef int i32x4 __attribute__((ext_vector_type(4)));
typedef unsigned short u16;
typedef unsigned short u16x4 __attribute__((ext_vector_type(4)));
typedef unsigned short u16x8 __attribute__((ext_vector_type(8)));
typedef unsigned int u32;

#define SEQ 1024
#define NBATCH 4
#define DM 1024
#define HD 4096
#define NV 32000
#define NVP 32768  // padded vocab (Ntiles = 256, divisible by 8 XCDs)
#define NT (SEQ * NBATCH)

__device__ __forceinline__ u16 f2bf(float f) {
  u32 u = __builtin_bit_cast(u32, f);
  return (u16)((u + 0x7FFFu + ((u >> 16) & 1u)) >> 16);  // RTNE
}
__device__ __forceinline__ float bf2f(u16 h) {
  return __builtin_bit_cast(float, (u32)h << 16);
}

// ---------------- fused f32 -> bf16 weight casts (4 segments, 2048 blocks) ----
__global__ __launch_bounds__(256) void cast_all_kernel(
    const float* __restrict__ wq, const float* __restrict__ wk,
    const float* __restrict__ wv, const float* __restrict__ wo,
    u16* __restrict__ wqk, u16* __restrict__ wvh, u16* __restrict__ woh) {
  long i = (long)blockIdx.x * 256 + threadIdx.x;
  const float* src;
  u16* dst;
  long off;
  if (i < 262144) {
    if (i < 131072) { src = wq; off = i; } else { src = wk; off = i - 131072; }
    dst = wqk + i * 8;  // contiguous QK pack
  } else if (i < 393216) {
    src = wv; off = i - 262144; dst = wvh + off * 8;
  } else {
    src = wo; off = i - 393216; dst = woh + off * 8;
  }
  const f32x4* p = (const f32x4*)(src + off * 8);
  f32x4 a = p[0], b = p[1];
  u16x8 o;
  o[0] = f2bf(a[0]); o[1] = f2bf(a[1]); o[2] = f2bf(a[2]); o[3] = f2bf(a[3]);
  o[4] = f2bf(b[0]); o[5] = f2bf(b[1]); o[6] = f2bf(b[2]); o[7] = f2bf(b[3]);
  *(u16x8*)dst = o;
}

// ---------------- embedding gather: f32 + bf16 copies ----------------
__global__ __launch_bounds__(256) void embed_kernel(const int* __restrict__ ids,
                                                    const float* __restrict__ tab,
                                                    float* __restrict__ ef,
                                                    u16* __restrict__ eh) {
  int t = blockIdx.x, tid = threadIdx.x;
  long id = ids[t];
  f32x4 v = *(const f32x4*)(tab + id * DM + tid * 4);
  *(f32x4*)(ef + (long)t * DM + tid * 4) = v;
  u16x4 h;
  h[0] = f2bf(v[0]); h[1] = f2bf(v[1]); h[2] = f2bf(v[2]); h[3] = f2bf(v[3]);
  *(u16x4*)(eh + (long)t * DM + tid * 4) = h;
}

// ---------------- row softmax (1024 cols), scale 1/32, bf16 out ----------------
__global__ __launch_bounds__(256) void softmax_kernel(const float* __restrict__ s,
                                                      u16* __restrict__ p) {
  int row = blockIdx.x, tid = threadIdx.x;
  const float* rp = s + (long)row * SEQ;
  f32x4 v = *(const f32x4*)(rp + tid * 4);
  float mx = fmaxf(fmaxf(v[0], v[1]), fmaxf(v[2], v[3]));
  for (int o = 32; o; o >>= 1) mx = fmaxf(mx, __shfl_xor(mx, o));
  __shared__ float red[4];
  if ((tid & 63) == 0) red[tid >> 6] = mx;
  __syncthreads();
  mx = fmaxf(fmaxf(red[0], red[1]), fmaxf(red[2], red[3]));
  const float sc = 0.03125f;  // 1/sqrt(1024)
  f32x4 e;
  e[0] = expf((v[0] - mx) * sc); e[1] = expf((v[1] - mx) * sc);
  e[2] = expf((v[2] - mx) * sc); e[3] = expf((v[3] - mx) * sc);
  float sm = e[0] + e[1] + e[2] + e[3];
  for (int o = 32; o; o >>= 1) sm += __shfl_xor(sm, o);
  __syncthreads();
  if ((tid & 63) == 0) red[tid >> 6] = sm;
  __syncthreads();
  sm = red[0] + red[1] + red[2] + red[3];
  float inv = 1.0f / sm;
  u16x4 o4;
  o4[0] = f2bf(e[0] * inv); o4[1] = f2bf(e[1] * inv);
  o4[2] = f2bf(e[2] * inv); o4[3] = f2bf(e[3] * inv);
  *(u16x4*)(p + (long)row * SEQ + tid * 4) = o4;
}

// ---------------- LayerNorm over D=1024; optional f32 and bf16 outputs ----------------
__global__ __launch_bounds__(256) void ln_kernel(const float* __restrict__ in,
                                                 const float* __restrict__ g,
                                                 const float* __restrict__ be,
                                                 float* __restrict__ outf,
                                                 u16* __restrict__ outh) {
  int row = blockIdx.x, tid = threadIdx.x;
  f32x4 v = *(const f32x4*)(in + (long)row * DM + tid * 4);
  float s = v[0] + v[1] + v[2] + v[3];
  float q = v[0] * v[0] + v[1] * v[1] + v[2] * v[2] + v[3] * v[3];
  for (int o = 32; o; o >>= 1) { s += __shfl_xor(s, o); q += __shfl_xor(q, o); }
  __shared__ float rs_[4], rq_[4];
  if ((tid & 63) == 0) { rs_[tid >> 6] = s; rq_[tid >> 6] = q; }
  __syncthreads();
  s = rs_[0] + rs_[1] + rs_[2] + rs_[3];
  q = rq_[0] + rq_[1] + rq_[2] + rq_[3];
  float mean = s * (1.0f / DM);
  float var = q * (1.0f / DM) - mean * mean;
  float rstd = rsqrtf(var + 1e-5f);
  f32x4 gg = *(const f32x4*)(g + tid * 4);
  f32x4 bb = *(const f32x4*)(be + tid * 4);
  f32x4 y;
  y[0] = (v[0] - mean) * rstd * gg[0] + bb[0];
  y[1] = (v[1] - mean) * rstd * gg[1] + bb[1];
  y[2] = (v[2] - mean) * rstd * gg[2] + bb[2];
  y[3] = (v[3] - mean) * rstd * gg[3] + bb[3];
  if (outf) *(f32x4*)(outf + (long)row * DM + tid * 4) = y;
  if (outh) {
    u16x4 h;
    h[0] = f2bf(y[0]); h[1] = f2bf(y[1]); h[2] = f2bf(y[2]); h[3] = f2bf(y[3]);
    *(u16x4*)(outh + (long)row * DM + tid * 4) = h;
  }
}

// ---------------- LayerNorm -> int8 per-row quant (+ optional f32 out) --------------
__global__ __launch_bounds__(256) void ln_i8_kernel(const float* __restrict__ in,
                                                    const float* __restrict__ g,
                                                    const float* __restrict__ be,
                                                    char* __restrict__ q8,
                                                    float* __restrict__ scale,
                                                    float* __restrict__ outf) {
  int row = blockIdx.x, tid = threadIdx.x;
  f32x4 v = *(const f32x4*)(in + (long)row * DM + tid * 4);
  float s = v[0] + v[1] + v[2] + v[3];
  float q = v[0] * v[0] + v[1] * v[1] + v[2] * v[2] + v[3] * v[3];
  for (int o = 32; o; o >>= 1) { s += __shfl_xor(s, o); q += __shfl_xor(q, o); }
  __shared__ float rs_[4], rq_[4], rm_[4];
  if ((tid & 63) == 0) { rs_[tid >> 6] = s; rq_[tid >> 6] = q; }
  __syncthreads();
  s = rs_[0] + rs_[1] + rs_[2] + rs_[3];
  q = rq_[0] + rq_[1] + rq_[2] + rq_[3];
  float mean = s * (1.0f / DM);
  float var = q * (1.0f / DM) - mean * mean;
  float rstd = rsqrtf(var + 1e-5f);
  f32x4 gg = *(const f32x4*)(g + tid * 4);
  f32x4 bb = *(const f32x4*)(be + tid * 4);
  f32x4 y;
  y[0] = (v[0] - mean) * rstd * gg[0] + bb[0];
  y[1] = (v[1] - mean) * rstd * gg[1] + bb[1];
  y[2] = (v[2] - mean) * rstd * gg[2] + bb[2];
  y[3] = (v[3] - mean) * rstd * gg[3] + bb[3];
  if (outf) *(f32x4*)(outf + (long)row * DM + tid * 4) = y;
  float am = fmaxf(fmaxf(fabsf(y[0]), fabsf(y[1])), fmaxf(fabsf(y[2]), fabsf(y[3])));
  for (int o = 32; o; o >>= 1) am = fmaxf(am, __shfl_xor(am, o));
  __syncthreads();
  if ((tid & 63) == 0) rm_[tid >> 6] = am;
  __syncthreads();
  am = fmaxf(fmaxf(rm_[0], rm_[1]), fmaxf(rm_[2], rm_[3]));
  float inv = (am > 0.f) ? 127.f / am : 0.f;
  int q0 = (int)rintf(y[0] * inv), q1 = (int)rintf(y[1] * inv);
  int q2 = (int)rintf(y[2] * inv), q3 = (int)rintf(y[3] * inv);
  u32 pk = (q0 & 255) | ((q1 & 255) << 8) | ((q2 & 255) << 16) | ((u32)(q3 & 255) << 24);
  *(u32*)(q8 + (size_t)row * DM + tid * 4) = pk;
  if (tid == 0) scale[row] = am * (1.0f / 127.f);
}

// ---------------- generic per-row f32 -> int8 quant (rowlen 1024/2048/3072/4096) ------
__global__ __launch_bounds__(256) void rowq_f32(const float* __restrict__ in,
                                                char* __restrict__ q8,
                                                float* __restrict__ scale, int rowlen) {
  const int row = blockIdx.x, tid = threadIdx.x;
  const float* rp = in + (size_t)row * rowlen;
  const int nch = rowlen >> 10;
  f32x4 v0 = {}, v1 = {}, v2 = {}, v3 = {};
  v0 = *(const f32x4*)(rp + tid * 4);
  if (nch > 1) v1 = *(const f32x4*)(rp + 1024 + tid * 4);
  if (nch > 2) v2 = *(const f32x4*)(rp + 2048 + tid * 4);
  if (nch > 3) v3 = *(const f32x4*)(rp + 3072 + tid * 4);
  auto am4 = [](f32x4 v) {
    return fmaxf(fmaxf(fabsf(v[0]), fabsf(v[1])), fmaxf(fabsf(v[2]), fabsf(v[3])));
  };
  float am = fmaxf(fmaxf(am4(v0), am4(v1)), fmaxf(am4(v2), am4(v3)));
  for (int o = 32; o; o >>= 1) am = fmaxf(am, __shfl_xor(am, o));
  __shared__ float rm_[4];
  if ((tid & 63) == 0) rm_[tid >> 6] = am;
  __syncthreads();
  am = fmaxf(fmaxf(rm_[0], rm_[1]), fmaxf(rm_[2], rm_[3]));
  const float inv = (am > 0.f) ? 127.f / am : 0.f;
  auto pack = [&](f32x4 v) {
    int q0 = (int)rintf(v[0] * inv), q1 = (int)rintf(v[1] * inv);
    int q2 = (int)rintf(v[2] * inv), q3 = (int)rintf(v[3] * inv);
    return (u32)((q0 & 255) | ((q1 & 255) << 8) | ((q2 & 255) << 16) | ((u32)(q3 & 255) << 24));
  };
  char* qp = q8 + (size_t)row * rowlen;
  *(u32*)(qp + tid * 4) = pack(v0);
  if (nch > 1) *(u32*)(qp + 1024 + tid * 4) = pack(v1);
  if (nch > 2) *(u32*)(qp + 2048 + tid * 4) = pack(v2);
  if (nch > 3) *(u32*)(qp + 3072 + tid * 4) = pack(v3);
  if (tid == 0) scale[row] = am * (1.0f / 127.f);
}

// ---------------- per-row bf16 -> int8 quant, rowlen = HD (h matrix) ----------------
__global__ __launch_bounds__(256) void rowq_bf16_hd(const u16* __restrict__ in,
                                                    char* __restrict__ q8,
                                                    float* __restrict__ scale) {
  const int row = blockIdx.x, tid = threadIdx.x;
  const u16* rp = in + (size_t)row * HD;
  f32x4 v0, v1, v2, v3;
  auto ld4 = [&](int off) {
    u16x4 h = *(const u16x4*)(rp + off + tid * 4);
    f32x4 v;
    v[0] = bf2f(h[0]); v[1] = bf2f(h[1]); v[2] = bf2f(h[2]); v[3] = bf2f(h[3]);
    return v;
  };
  v0 = ld4(0); v1 = ld4(1024); v2 = ld4(2048); v3 = ld4(3072);
  auto am4 = [](f32x4 v) {
    return fmaxf(fmaxf(fabsf(v[0]), fabsf(v[1])), fmaxf(fabsf(v[2]), fabsf(v[3])));
  };
  float am = fmaxf(fmaxf(am4(v0), am4(v1)), fmaxf(am4(v2), am4(v3)));
  for (int o = 32; o; o >>= 1) am = fmaxf(am, __shfl_xor(am, o));
  __shared__ float rm_[4];
  if ((tid & 63) == 0) rm_[tid >> 6] = am;
  __syncthreads();
  am = fmaxf(fmaxf(rm_[0], rm_[1]), fmaxf(rm_[2], rm_[3]));
  const float inv = (am > 0.f) ? 127.f / am : 0.f;
  auto pack = [&](f32x4 v) {
    int q0 = (int)rintf(v[0] * inv), q1 = (int)rintf(v[1] * inv);
    int q2 = (int)rintf(v[2] * inv), q3 = (int)rintf(v[3] * inv);
    return (u32)((q0 & 255) | ((q1 & 255) << 8) | ((q2 & 255) << 16) | ((u32)(q3 & 255) << 24));
  };
  char* qp = q8 + (size_t)row * HD;
  *(u32*)(qp + tid * 4) = pack(v0);
  *(u32*)(qp + 1024 + tid * 4) = pack(v1);
  *(u32*)(qp + 2048 + tid * 4) = pack(v2);
  *(u32*)(qp + 3072 + tid * 4) = pack(v3);
  if (tid == 0) scale[row] = am * (1.0f / 127.f);
}

#define GLD(gp, lp)                                              \
  __builtin_amdgcn_global_load_lds(                              \
      (__attribute__((address_space(1))) void*)(gp),             \
      (__attribute__((address_space(3))) void*)(lp), 16, 0, 0)

// ---------------- generic bf16 GEMM (m97 structure): C = A (MxK) * B^T ----------------
#define BM 128
#define BN 128
#define BK 32

__global__ __launch_bounds__(256) void gemm_bt(
    const u16* __restrict__ A, const u16* __restrict__ B,
    float* __restrict__ Cf, u16* __restrict__ Ch,
    const float* __restrict__ bias, const float* __restrict__ resid,
    int K, int lda, int ldb, int ldc,
    long batA, long batB, long batC, int relu) {
  __shared__ u16 As[BM * BK];
  __shared__ u16 Bs[BN * BK];
  const int tid = threadIdx.x;
  const int bz = blockIdx.z;
  A += (long)bz * batA;
  B += (long)bz * batB;
  const long cbase = (long)bz * batC;
  const int row0 = blockIdx.y * BM;
  const int col0 = blockIdx.x * BN;
  const int l = tid & 63;
  const int w = tid >> 6;
  const int wr = (w >> 1) * 64, wc = (w & 1) * 64;

  f32x4 acc[4][4] = {};

  const u16* gA = A + (long)(row0 + (tid >> 2)) * lda + (tid & 3) * 8;
  const u16* gB = B + (long)(col0 + (tid >> 2)) * ldb + (tid & 3) * 8;
  const long a64 = (long)64 * lda, b64 = (long)64 * ldb;
  u16* lA = As + tid * 8;
  u16* lB = Bs + tid * 8;

  const int fr = l & 15;
  const int fk = (l >> 4) * 8;
  const u16* rA = As + (wr + fr) * BK + fk;
  const u16* rB = Bs + (wc + fr) * BK + fk;

  for (int k0 = 0; k0 < K; k0 += BK) {
    GLD(gA + k0, lA);
    GLD(gA + a64 + k0, lA + 2048);
    GLD(gB + k0, lB);
    GLD(gB + b64 + k0, lB + 2048);
    __syncthreads();
    bf16x8 af[4], bf[4];
#pragma unroll
    for (int m = 0; m < 4; ++m) af[m] = *(const bf16x8*)(rA + m * 16 * BK);
#pragma unroll
    for (int n = 0; n < 4; ++n) bf[n] = *(const bf16x8*)(rB + n * 16 * BK);
#pragma unroll
    for (int m = 0; m < 4; ++m)
#pragma unroll
      for (int n = 0; n < 4; ++n)
        acc[m][n] = __builtin_amdgcn_mfma_f32_16x16x32_bf16(af[m], bf[n], acc[m][n], 0, 0, 0);
    __syncthreads();
  }

  const int er = row0 + wr + ((l >> 4) << 2);
  const int ec = col0 + wc + (l & 15);
#pragma unroll
  for (int m = 0; m < 4; ++m) {
#pragma unroll
    for (int n = 0; n < 4; ++n) {
      f32x4 v = acc[m][n];
      const int c = ec + n * 16;
      float bv = bias ? bias[c] : 0.0f;
#pragma unroll
      for (int i = 0; i < 4; ++i) {
        const int r = er + m * 16 + i;
        float x = v[i] + bv;
        if (resid) x += resid[(long)r * ldc + c];
        if (relu) x = fmaxf(x, 0.0f);
        if (Cf) Cf[cbase + (long)r * ldc + c] = x;
        if (Ch) Ch[cbase + (long)r * ldc + c] = f2bf(x);
      }
    }
  }
}

#define DSB() __builtin_amdgcn_sched_barrier(0)
#define SBAR() __builtin_amdgcn_s_barrier()

// ---------------- int8 GEMM, depth-2 prefetch, STATIC 3-buffer (round-13 proven) -------
// 128x128 tile, BK=64, mfma_i32_16x16x64_i8. nkt % 3 == 1. XCD chunk + N-fast order.
// Optional: f32 out (Cf), bf16 out (Ch), f32 resid, relu.
__global__ __launch_bounds__(256) void gemm_i8(
    const char* __restrict__ A, const char* __restrict__ B,
    float* __restrict__ Cf, u16* __restrict__ Ch,
    const float* __restrict__ sA, const float* __restrict__ sB,
    const float* __restrict__ bias, const float* __restrict__ resid,
    int K, int lda, int ldb, int ldc, int Mtiles, int Ntiles, int relu) {
  __shared__ __align__(16) char As[3][128 * 64];
  __shared__ __align__(16) char Bs[3][128 * 64];
  const int tid = threadIdx.x;

  const int nwg = gridDim.x;
  const int blk = blockIdx.x;
  const int cpx = nwg >> 3;
  const int wg = (blk & 7) * cpx + (blk >> 3);
  const int row0 = (wg / Ntiles) * 128;
  const int col0 = (wg % Ntiles) * 128;

  const int l = tid & 63;
  const int w = tid >> 6;
  const int wr = (w >> 1) * 64, wc = (w & 1) * 64;

  const int srow = tid >> 2;
  const int sslot = (tid & 3) ^ ((srow >> 1) & 3);
  const char* gA = A + (size_t)(row0 + srow) * lda + sslot * 16;
  const char* gB = B + (size_t)(col0 + srow) * ldb + sslot * 16;
  const size_t a64 = (size_t)64 * lda, b64 = (size_t)64 * ldb;

#define STAGE_I8(buf, kt)                                            \
  do {                                                               \
    const char* _ga = gA + (size_t)(kt) * 64;                        \
    const char* _gb = gB + (size_t)(kt) * 64;                        \
    GLD(_ga, &As[buf][0] + tid * 16);                                \
    GLD(_ga + a64, &As[buf][4096] + tid * 16);                       \
    GLD(_gb, &Bs[buf][0] + tid * 16);                                \
    GLD(_gb + b64, &Bs[buf][4096] + tid * 16);                       \
  } while (0)

  const int fr = l & 15;
  const int fsw = 16 * ((l >> 4) ^ ((fr >> 1) & 3));
  const int raoff = (wr + fr) * 64 + fsw;
  const int rboff = (wc + fr) * 64 + fsw;

  i32x4 acc[4][4] = {};

#define COMPUTE_I8(buf)                                                         \
  do {                                                                          \
    i32x4 af[4], bf[4];                                                         \
    _Pragma("unroll")                                                           \
    for (int m = 0; m < 4; ++m) af[m] = *(const i32x4*)(&As[buf][raoff + m * 1024]); \
    _Pragma("unroll")                                                           \
    for (int n = 0; n < 4; ++n) bf[n] = *(const i32x4*)(&Bs[buf][rboff + n * 1024]); \
    _Pragma("unroll")                                                           \
    for (int m = 0; m < 4; ++m)                                                 \
      _Pragma("unroll")                                                         \
      for (int n = 0; n < 4; ++n)                                               \
        acc[m][n] = __builtin_amdgcn_mfma_i32_16x16x64_i8(af[m], bf[n], acc[m][n], 0, 0, 0); \
  } while (0)

#define PIPE_STEP(bufS, kt, bufC)                    \
  do {                                               \
    STAGE_I8(bufS, kt);                              \
    COMPUTE_I8(bufC);                                \
    asm volatile("s_waitcnt vmcnt(4)"); DSB();       \
    SBAR();                                          \
  } while (0)

  const int nkt = K >> 6;  // nkt % 3 == 1 (16 for K=1024, 64 for K=4096)

  STAGE_I8(0, 0);
  STAGE_I8(1, 1);
  asm volatile("s_waitcnt vmcnt(4)"); DSB();
  SBAR();

  for (int t = 0; t + 7 <= nkt; t += 3) {
    PIPE_STEP(2, t + 2, 0);
    PIPE_STEP(0, t + 3, 1);
    PIPE_STEP(1, t + 4, 2);
  }
  PIPE_STEP(2, nkt - 2, 0);
  PIPE_STEP(0, nkt - 1, 1);
  COMPUTE_I8(2);
  asm volatile("s_waitcnt vmcnt(0)"); DSB();
  SBAR();
  COMPUTE_I8(0);

  const int er = row0 + wr + ((l >> 4) << 2);
  const int ec = col0 + wc + (l & 15);
#pragma unroll
  for (int m = 0; m < 4; ++m) {
#pragma unroll
    for (int n = 0; n < 4; ++n) {
      i32x4 v = acc[m][n];
      const int c = ec + n * 16;
      const float sb = sB[c];
      const float bv = bias ? bias[c] : 0.0f;
#pragma unroll
      for (int i = 0; i < 4; ++i) {
        const int r = er + m * 16 + i;
        float x = (float)v[i] * (sA[r] * sb) + bv;
        if (resid) x += resid[(size_t)r * ldc + c];
        if (relu) x = fmaxf(x, 0.0f);
        if (Cf) Cf[(size_t)r * ldc + c] = x;
        if (Ch) Ch[(size_t)r * ldc + c] = f2bf(x);
      }
    }
  }
#undef STAGE_I8
#undef COMPUTE_I8
#undef PIPE_STEP
}

// ---------------- int8 GEMM, N-SLICED XCD ownership (logits; round-16 proven) ---------
__global__ __launch_bounds__(256) void gemm_i8_ns(
    const char* __restrict__ A, const char* __restrict__ B,
    float* __restrict__ C, const float* __restrict__ sA, const float* __restrict__ sB,
    const float* __restrict__ bias, int K, int lda, int ldb, int ldc,
    int Mtiles, int Ntiles, int validN) {
  __shared__ __align__(16) char As[3][128 * 64];
  __shared__ __align__(16) char Bs[3][128 * 64];
  const int tid = threadIdx.x;

  const int blk = blockIdx.x;
  const int xcd = blk & 7;
  const int local = blk >> 3;
  const int nsl = Ntiles >> 3;
  const int m = local / nsl;
  const int nl = local - m * nsl;
  const int row0 = m * 128;
  const int col0 = (xcd * nsl + nl) * 128;

  const int l = tid & 63;
  const int w = tid >> 6;
  const int wr = (w >> 1) * 64, wc = (w & 1) * 64;

  const int srow = tid >> 2;
  const int sslot = (tid & 3) ^ ((srow >> 1) & 3);
  const char* gA = A + (size_t)(row0 + srow) * lda + sslot * 16;
  const char* gB = B + (size_t)(col0 + srow) * ldb + sslot * 16;
  const size_t a64 = (size_t)64 * lda, b64 = (size_t)64 * ldb;

#define STAGE_NS(buf, kt)                                            \
  do {                                                               \
    const char* _ga = gA + (size_t)(kt) * 64;                        \
    const char* _gb = gB + (size_t)(kt) * 64;                        \
    GLD(_ga, &As[buf][0] + tid * 16);                                \
    GLD(_ga + a64, &As[buf][4096] + tid * 16);                       \
    GLD(_gb, &Bs[buf][0] + tid * 16);                                \
    GLD(_gb + b64, &Bs[buf][4096] + tid * 16);                       \
  } while (0)

  const int fr = l & 15;
  const int fsw = 16 * ((l >> 4) ^ ((fr >> 1) & 3));
  const int raoff = (wr + fr) * 64 + fsw;
  const int rboff = (wc + fr) * 64 + fsw;

  i32x4 acc[4][4] = {};

#define COMPUTE_NS(buf)                                                         \
  do {                                                                          \
    i32x4 af[4], bf[4];                                                         \
    _Pragma("unroll")                                                           \
    for (int m_ = 0; m_ < 4; ++m_) af[m_] = *(const i32x4*)(&As[buf][raoff + m_ * 1024]); \
    _Pragma("unroll")                                                           \
    for (int n_ = 0; n_ < 4; ++n_) bf[n_] = *(const i32x4*)(&Bs[buf][rboff + n_ * 1024]); \
    _Pragma("unroll")                                                           \
    for (int m_ = 0; m_ < 4; ++m_)                                              \
      _Pragma("unroll")                                                         \
      for (int n_ = 0; n_ < 4; ++n_)                                            \
        acc[m_][n_] = __builtin_amdgcn_mfma_i32_16x16x64_i8(af[m_], bf[n_], acc[m_][n_], 0, 0, 0); \
  } while (0)

#define PIPE_NS(bufS, kt, bufC)                      \
  do {                                               \
    STAGE_NS(bufS, kt);                              \
    COMPUTE_NS(bufC);                                \
    asm volatile("s_waitcnt vmcnt(4)"); DSB();       \
    SBAR();                                          \
  } while (0)

  const int nkt = K >> 6;

  STAGE_NS(0, 0);
  STAGE_NS(1, 1);
  asm volatile("s_waitcnt vmcnt(4)"); DSB();
  SBAR();

  for (int t = 0; t + 7 <= nkt; t += 3) {
    PIPE_NS(2, t + 2, 0);
    PIPE_NS(0, t + 3, 1);
    PIPE_NS(1, t + 4, 2);
  }
  PIPE_NS(2, nkt - 2, 0);
  PIPE_NS(0, nkt - 1, 1);
  COMPUTE_NS(2);
  asm volatile("s_waitcnt vmcnt(0)"); DSB();
  SBAR();
  COMPUTE_NS(0);

  const int er = row0 + wr + ((l >> 4) << 2);
  const int ec = col0 + wc + (l & 15);
#pragma unroll
  for (int m_ = 0; m_ < 4; ++m_) {
#pragma unroll
    for (int n_ = 0; n_ < 4; ++n_) {
      i32x4 v = acc[m_][n_];
      const int c = ec + n_ * 16;
      if (c >= validN) continue;
      const float sb = sB[c];
      const float bv = bias ? bias[c] : 0.0f;
#pragma unroll
      for (int i = 0; i < 4; ++i) {
        const int r = er + m_ * 16 + i;
        C[(size_t)r * ldc + c] = (float)v[i] * (sA[r] * sb) + bv;
      }
    }
  }
#undef STAGE_NS
#undef COMPUTE_NS
#undef PIPE_NS
}

extern "C" void kernel_launch(void* const* d_in, const int* in_sizes, int n_in,
                              void* d_out, int out_size, void* d_ws, size_t ws_size,
                              hipStream_t stream) {
  const int* ids = (const int*)d_in[0];
  const float* tab = (const float*)d_in[1];
  const float* WQ = (const float*)d_in[2];
  const float* WK = (const float*)d_in[3];
  const float* WV = (const float*)d_in[4];
  const float* Wo = (const float*)d_in[5];
  const float* bo = (const float*)d_in[6];
  const float* W1 = (const float*)d_in[7];
  const float* b1 = (const float*)d_in[8];
  const float* W2 = (const float*)d_in[9];
  const float* b2 = (const float*)d_in[10];
  const float* g1 = (const float*)d_in[11];
  const float* be1 = (const float*)d_in[12];
  const float* g2 = (const float*)d_in[13];
  const float* be2 = (const float*)d_in[14];
  const float* Wd = (const float*)d_in[15];
  const float* bd = (const float*)d_in[16];
  float* logits = (float*)d_out;

  if (ws_size < 280000000ull) return;

  char* p = (char*)d_ws;
  auto alloc = [&](size_t bytes) {
    char* r = p;
    p += (bytes + 255) & ~(size_t)255;
    return r;
  };
  float* embf = (float*)alloc((size_t)NT * DM * 4);
  u16* embh = (u16*)alloc((size_t)NT * DM * 2);
  u16* WQKh = (u16*)alloc((size_t)2 * DM * DM * 2);  // [2048][1024] packed WQ;WK
  u16* WVh = (u16*)alloc((size_t)DM * DM * 2);
  u16* Woh = (u16*)alloc((size_t)DM * DM * 2);
  char* W1q = (char*)alloc((size_t)HD * DM);         // int8 W1
  float* sW1 = (float*)alloc((size_t)HD * 4);
  char* W2q = (char*)alloc((size_t)DM * HD);         // int8 W2
  float* sW2 = (float*)alloc((size_t)DM * 4);
  char* Wdq = (char*)alloc((size_t)NVP * DM);        // int8 Wd, padded to 32768 rows
  float* sWd = (float*)alloc((size_t)NVP * 4);
  u16* QKh = (u16*)alloc((size_t)NT * 2 * DM * 2);   // [NT][2048]: Q | K
  u16* VTh = (u16*)alloc((size_t)NBATCH * DM * SEQ * 2);
  float* scoresf = (float*)alloc((size_t)NBATCH * SEQ * SEQ * 4);
  u16* Ph = (u16*)alloc((size_t)NBATCH * SEQ * SEQ * 2);
  u16* zh = (u16*)alloc((size_t)NT * DM * 2);
  float* r1f = (float*)alloc((size_t)NT * DM * 4);
  float* xf = (float*)alloc((size_t)NT * DM * 4);
  char* xq = (char*)alloc((size_t)NT * DM);          // int8 LN1 output
  float* sX = (float*)alloc((size_t)NT * 4);
  u16* hh = (u16*)alloc((size_t)NT * HD * 2);
  char* hq = (char*)alloc((size_t)NT * HD);          // int8 h
  float* sH = (float*)alloc((size_t)NT * 4);
  float* r2f = (float*)alloc((size_t)NT * DM * 4);
  char* outq = (char*)alloc((size_t)NT * DM);
  float* sOut = (float*)alloc((size_t)NT * 4);

  // --- weight casts (4 segments, 2048 blocks) + int8 weight quants ---
  cast_all_kernel<<<dim3(2048), 256, 0, stream>>>(WQ, WK, WV, Wo, WQKh, WVh, Woh);
  rowq_f32<<<dim3(NV), 256, 0, stream>>>(Wd, Wdq, sWd, DM);
  rowq_f32<<<dim3(HD), 256, 0, stream>>>(W1, W1q, sW1, DM);
  rowq_f32<<<dim3(DM), 256, 0, stream>>>(W2, W2q, sW2, HD);

  // --- embedding ---
  embed_kernel<<<NT, 256, 0, stream>>>(ids, tab, embf, embh);

  // --- fused Q,K projection: QK[t][0..1023]=Q, [1024..2047]=K ---
  gemm_bt<<<dim3(2 * DM / BN, NT / BM, 1), 256, 0, stream>>>(
      embh, WQKh, nullptr, QKh, nullptr, nullptr, DM, DM, DM, 2 * DM, 0, 0, 0, 0);

  // --- V^T per batch ---
  gemm_bt<<<dim3(SEQ / BN, DM / BM, NBATCH), 256, 0, stream>>>(
      WVh, embh, nullptr, VTh, nullptr, nullptr, DM, DM, NBATCH * DM, SEQ,
      0, DM, (long)DM * SEQ, 0);

  // --- scores ---
  gemm_bt<<<dim3(SEQ / BN, SEQ / BM, NBATCH), 256, 0, stream>>>(
      QKh, QKh + DM, scoresf, nullptr, nullptr, nullptr, DM,
      NBATCH * 2 * DM, NBATCH * 2 * DM, SEQ,
      2 * DM, 2 * DM, (long)SEQ * SEQ, 0);

  softmax_kernel<<<NBATCH * SEQ, 256, 0, stream>>>(scoresf, Ph);

  // --- Z = P @ V^T ---
  gemm_bt<<<dim3(DM / BN, SEQ / BM, NBATCH), 256, 0, stream>>>(
      Ph, VTh, nullptr, zh, nullptr, nullptr, SEQ, SEQ, SEQ, NBATCH * DM,
      (long)SEQ * SEQ, (long)DM * SEQ, DM, 0);

  // --- r1 = z @ Wo^T + bo + emb ---
  gemm_bt<<<dim3(DM / BN, NT / BM, 1), 256, 0, stream>>>(
      zh, Woh, r1f, nullptr, bo, embf, DM, DM, DM, DM, 0, 0, 0, 0);

  // --- LN1 -> int8 (+ f32 for FFN2 resid) ---
  ln_i8_kernel<<<NT, 256, 0, stream>>>(r1f, g1, be1, xq, sX, xf);

  // --- FFN1: int8 GEMM (K=1024, nkt=16), relu, bf16 out ---
  gemm_i8<<<dim3((NT / 128) * (HD / 128)), 256, 0, stream>>>(
      xq, W1q, nullptr, hh, sX, sW1, b1, nullptr, DM, DM, DM, HD,
      NT / 128, HD / 128, 1);

  // --- h -> int8 per-row ---
  rowq_bf16_hd<<<dim3(NT), 256, 0, stream>>>(hh, hq, sH);

  // --- FFN2: int8 GEMM depth-2 (K=4096, nkt=64), resid = xf, bias = b2 ---
  gemm_i8<<<dim3((NT / 128) * (DM / 128)), 256, 0, stream>>>(
      hq, W2q, r2f, nullptr, sH, sW2, b2, xf, HD, HD, HD, DM,
      NT / 128, DM / 128, 0);

  // --- LN2 -> int8 + per-row scale ---
  ln_i8_kernel<<<NT, 256, 0, stream>>>(r2f, g2, be2, outq, sOut, nullptr);

  // --- logits: int8 GEMM, N-sliced XCD ownership (grid 32 x 256 = 8192 blocks) ---
  gemm_i8_ns<<<dim3((NT / 128) * (NVP / 128)), 256, 0, stream>>>(
      outq, Wdq, logits, sOut, sWd, bd, DM, DM, DM, NV,
      NT / 128, NVP / 128, NV);
}